// Round 12
// baseline (448.203 us; speedup 1.0000x reference)
//
#include <hip/hip_runtime.h>

// Problem constants
#define T_ 64
#define B_ 512
#define D_ 768
#define H_ 12
#define HD_ 64
#define M1 (T_*B_)        // 32768 rows for both GEMMs
#define N_QKV (3*D_)      // 2304

typedef __attribute__((ext_vector_type(8))) short short8;
typedef __attribute__((ext_vector_type(4))) float f32x4;

__device__ __forceinline__ unsigned short f2b(float f) {
  unsigned int u = __float_as_uint(f);
  u = (u + 0x7FFFu + ((u >> 16) & 1u)) >> 16;   // RNE
  return (unsigned short)u;
}
__device__ __forceinline__ float b2f(unsigned short s) {
  return __uint_as_float(((unsigned int)s) << 16);
}

// async 16B global -> LDS. ALWAYS offset=0 (verified semantics); offsets are
// folded into the global pointer.
__device__ __forceinline__ void load_lds16(const unsigned short* g, unsigned short* l) {
  __builtin_amdgcn_global_load_lds(
      (const __attribute__((address_space(1))) unsigned int*)g,
      (__attribute__((address_space(3))) unsigned int*)l, 16, 0, 0);
}

// ---- fused fp32 -> bf16 casts (node / wqkv / wout in one launch) ----
#define N4_NODE 6291456
#define N4_WQKV 442368
#define N4_WOUT 147456
__global__ __launch_bounds__(256) void k_cast_all(
    const float* __restrict__ node, const float* __restrict__ wqkv,
    const float* __restrict__ wout, unsigned short* __restrict__ x_bf,
    unsigned short* __restrict__ wqkv_bf, unsigned short* __restrict__ wout_bf) {
  int i = blockIdx.x * 256 + threadIdx.x;
  const float* src; unsigned short* dst; int off;
  if (i < N4_NODE)                 { src = node; dst = x_bf;    off = i; }
  else if (i < N4_NODE + N4_WQKV)  { src = wqkv; dst = wqkv_bf; off = i - N4_NODE; }
  else                             { src = wout; dst = wout_bf; off = i - N4_NODE - N4_WQKV; }
  float4 v = ((const float4*)src)[off];
  ushort4 o;
  o.x = f2b(v.x); o.y = f2b(v.y); o.z = f2b(v.z); o.w = f2b(v.w);
  ((ushort4*)dst)[off] = o;
}

// =====================================================================
// m201-style two-barrier-phase ring GEMM: tile 256x256, K-granule 32
// (24 granules), ring-of-4 x 32 KiB = 128 KiB LDS, stage-ahead 3.
// (Round-11 verified best-passing GEMM structure; MfmaUtil ~33% is the
// structural floor for this K=768 shape — plateaued, kept as-is.)
// =====================================================================
#define SB0() __builtin_amdgcn_sched_barrier(0)
#define BARF() do { SB0(); __builtin_amdgcn_s_barrier(); SB0(); } while (0)
#define WLG0() asm volatile("s_waitcnt lgkmcnt(0)" ::: "memory")
#define WVM8() asm volatile("s_waitcnt vmcnt(8)" ::: "memory")
#define WVM6() asm volatile("s_waitcnt vmcnt(6)" ::: "memory")
#define WVM4() asm volatile("s_waitcnt vmcnt(4)" ::: "memory")
#define WVM2() asm volatile("s_waitcnt vmcnt(2)" ::: "memory")
#define WVM0() asm volatile("s_waitcnt vmcnt(0)" ::: "memory")

// 98304 = 128*768 shorts = 128 source rows.
#define STG_A(SLOT, GOFF) do { \
  load_lds16(Ag + (GOFF),          lds + (SLOT)*16384 + tid*8); \
  load_lds16(Ag + 98304 + (GOFF),  lds + (SLOT)*16384 + 4096 + tid*8); \
} while (0)
#define STG_B(SLOT, GOFF) do { \
  load_lds16(Bg0 + (GOFF),          lds + (SLOT)*16384 + 8192 + tid*8); \
  load_lds16(Bg0 + 98304 + (GOFF),  lds + (SLOT)*16384 + 12288 + tid*8); \
} while (0)

#define RD_ALO(PAR, SLOT) do { \
  const unsigned short* p_ = lds + (SLOT)*16384 + aBase; \
  aLo[PAR][0] = *(const short8*)(p_); \
  aLo[PAR][1] = *(const short8*)(p_ + 512); \
  aLo[PAR][2] = *(const short8*)(p_ + 1024); \
  aLo[PAR][3] = *(const short8*)(p_ + 1536); \
} while (0)

#define RD_BHI(SLOT) do { \
  const unsigned short* pb_ = lds + (SLOT)*16384 + bBase; \
  bC[0] = *(const short8*)(pb_); \
  bC[1] = *(const short8*)(pb_ + 512); \
  bC[2] = *(const short8*)(pb_ + 1024); \
  bC[3] = *(const short8*)(pb_ + 1536); \
  const unsigned short* pa_ = lds + (SLOT)*16384 + aBase + 2048; \
  aHi[0] = *(const short8*)(pa_); \
  aHi[1] = *(const short8*)(pa_ + 512); \
  aHi[2] = *(const short8*)(pa_ + 1024); \
  aHi[3] = *(const short8*)(pa_ + 1536); \
} while (0)

#define MM_LO(PAR) do { \
  __builtin_amdgcn_s_setprio(1); \
  _Pragma("unroll") \
  for (int mf = 0; mf < 4; mf++) \
    _Pragma("unroll") \
    for (int nf = 0; nf < 4; nf++) \
      acc[mf][nf] = __builtin_amdgcn_mfma_f32_16x16x32_bf16(aLo[PAR][mf], bC[nf], acc[mf][nf], 0, 0, 0); \
  __builtin_amdgcn_s_setprio(0); \
} while (0)

#define MM_HI() do { \
  __builtin_amdgcn_s_setprio(1); \
  _Pragma("unroll") \
  for (int mf = 0; mf < 4; mf++) \
    _Pragma("unroll") \
    for (int nf = 0; nf < 4; nf++) \
      acc[4+mf][nf] = __builtin_amdgcn_mfma_f32_16x16x32_bf16(aHi[mf], bC[nf], acc[4+mf][nf], 0, 0, 0); \
  __builtin_amdgcn_s_setprio(0); \
} while (0)

#define P0(SLOT, PAR, SSLOT, GOFF, WVSTMT) do { \
  RD_BHI(SLOT); STG_A(SSLOT, GOFF); WVSTMT; BARF(); WLG0(); MM_LO(PAR); BARF(); \
} while (0)
#define P1(NPAR, NSLOT, SSLOT, GOFF) do { \
  RD_ALO(NPAR, NSLOT); STG_B(SSLOT, GOFF); BARF(); MM_HI(); BARF(); \
} while (0)

// K-loop: prologue stages g0-g2 + reads aLo(0); g0 phases stage g3;
// J-loop covers g1..g20 (stages g4..g23); peel g21-g23 drains.
#define GEMM_RING_KLOOP(Aptr, Bptr) \
  const int tid = threadIdx.x; \
  const int lane = tid & 63, wave = tid >> 6; \
  const int ln = lane & 15, quad = lane >> 4; \
  const int wm = wave & 1, wn = wave >> 1; \
  /* staging: lane tid fills slot tid; inverse of slot map gives source */ \
  const int w_ = tid & 7, g_ = tid >> 3; \
  const int rowS_ = ((g_ >> 2) << 3) + (w_ & 4) + (g_ & 3); \
  const int octS_ = (w_ & 3) ^ (g_ & 3); \
  const unsigned short* Ag = Aptr + (size_t)(m0 + rowS_)*768 + octS_*8; \
  const unsigned short* Bg0 = Bptr + (size_t)(n0 + rowS_)*768 + octS_*8; \
  /* frag read bases: slot(row,oct)=((row>>3)*4+(row&3))*8+((row&7)^oct) */ \
  const int inner_ = (((ln>>3)*4 + (ln&3))*8 + ((ln&7) ^ quad)) * 8; \
  const int aBase = wm*4096 + inner_; \
  const int bBase = 8192 + (wn>>1)*4096 + (wn&1)*2048 + inner_; \
  short8 aLo[2][4], aHi[4], bC[4]; \
  f32x4 acc[8][4] = {}; \
  STG_A(0, 0); STG_B(0, 0); STG_A(1, 32); STG_B(1, 32); STG_A(2, 64); STG_B(2, 64); \
  WVM8(); BARF(); \
  RD_ALO(0, 0); \
  /* g0: slot0 par0; stage g3 slot3 goff96 */ \
  P0(0, 0, 3, 96, WVM6()); \
  P1(1, 1, 3, 96); \
  for (int J = 0; J < 5; ++J) { \
    P0(1, 1, 0, 128, WVM6()); \
    P1(0, 2, 0, 128); \
    P0(2, 0, 1, 160, WVM6()); \
    P1(1, 3, 1, 160); \
    P0(3, 1, 2, 192, WVM6()); \
    P1(0, 0, 2, 192); \
    P0(0, 0, 3, 224, WVM6()); \
    P1(1, 1, 3, 224); \
    Ag += 128; Bg0 += 128; \
  } \
  /* peel g21 (slot1,par1), g22 (slot2,par0), g23 (slot3,par1) */ \
  RD_BHI(1); WVM4(); BARF(); WLG0(); MM_LO(1); BARF(); \
  RD_ALO(0, 2); BARF(); MM_HI(); BARF(); \
  RD_BHI(2); WVM0(); BARF(); WLG0(); MM_LO(0); BARF(); \
  RD_ALO(1, 3); BARF(); MM_HI(); BARF(); \
  RD_BHI(3); BARF(); WLG0(); MM_LO(1); BARF(); \
  MM_HI(); \
  __syncthreads();

// ---- QKV projection, ring GEMM 256x256. XCD-swizzled; LDS-repack epilogues.
__global__ __launch_bounds__(512, 2) void k_gemm_qkv8(
    const unsigned short* __restrict__ A,    // [32768,768] bf16
    const unsigned short* __restrict__ Bw,   // [2304,768]  bf16
    const float* __restrict__ bias,          // [2304]
    unsigned short* __restrict__ qo,
    unsigned short* __restrict__ ko,
    unsigned short* __restrict__ vTo)
{
  extern __shared__ __align__(16) unsigned short lds[];   // 128 KiB
  const int bb = blockIdx.x;                 // 1152 blocks
  const int xcd = bb & 7, idx = bb >> 3;     // idx in [0,144)
  const int m0 = (xcd*16 + idx/9) * 256;     // same-XCD blocks share m-stripe
  const int n0 = (idx%9) * 256;              // n sweeps fastest -> A L2 reuse
  GEMM_RING_KLOOP(A, Bw)

  const int t = m0 >> 9, mb = m0 & 511;
  if (n0 < 1536) {
    // q/k: two 128-row halves; repack [row][col] (chunk^row swizzle) + store
    unsigned short* dst = (n0 < 768) ? qo : ko;
    const int colbase = (n0 < 768) ? n0 : n0 - 768;
#pragma unroll
    for (int half = 0; half < 2; half++) {
      __syncthreads();
      if (wm == half) {
#pragma unroll
        for (int nf = 0; nf < 4; nf++) {
          const int col = wn*64 + nf*16 + ln;
          const float bi = bias[n0 + col];
          const int cc = col >> 3, cs = col & 7;
#pragma unroll
          for (int mf = 0; mf < 8; mf++) {
            const int row = mf*16 + quad*4;       // local to half
#pragma unroll
            for (int r = 0; r < 4; r++) {
              const int rw = row + r;
              lds[rw*256 + ((cc ^ (rw&7))<<3) + cs] = f2b(acc[mf][nf][r] + bi);
            }
          }
        }
      }
      __syncthreads();
#pragma unroll
      for (int it = 0; it < 8; it++) {
        int ci = it*512 + tid;
        int r2 = ci >> 5, cj = ci & 31;
        int within = colbase + cj*8;
        int h = within >> 6, hd = within & 63;
        *(uint4*)&dst[((size_t)(t*H_ + h)*B_ + mb + half*128 + r2)*HD_ + hd] =
            *(const uint4*)&lds[r2*256 + ((cj ^ (r2&7))<<3)];
      }
    }
  } else {
    // v: two 128-col halves; repack transposed [col][b-row] + store
#pragma unroll
    for (int ch = 0; ch < 2; ch++) {
      __syncthreads();
      if ((wn >> 1) == ch) {
#pragma unroll
        for (int nf = 0; nf < 4; nf++) {
          const int col = wn*64 + nf*16 + ln;
          const int cl = col & 127;               // local to col-half
          const float bi = bias[n0 + col];
#pragma unroll
          for (int mf = 0; mf < 8; mf++) {
            const int row = wm*128 + mf*16 + quad*4;   // 0..255
            ushort4 pk;
            pk.x = f2b(acc[mf][nf][0] + bi);
            pk.y = f2b(acc[mf][nf][1] + bi);
            pk.z = f2b(acc[mf][nf][2] + bi);
            pk.w = f2b(acc[mf][nf][3] + bi);
            *(ushort4*)&lds[cl*256 + (((row>>3) ^ (cl&7))<<3) + (row&7)] = pk;
          }
        }
      }
      __syncthreads();
#pragma unroll
      for (int it = 0; it < 8; it++) {
        int ci = it*512 + tid;
        int r2 = ci >> 5, cj = ci & 31;     // r2 = col-local, cj = b-chunk
        int cg = (n0 - 1536) + ch*128 + r2;
        int h = cg >> 6, hd = cg & 63;
        *(uint4*)&vTo[((size_t)(t*H_ + h)*HD_ + hd)*B_ + mb + cj*8] =
            *(const uint4*)&lds[r2*256 + ((cj ^ (r2&7))<<3)];
      }
    }
  }
}

// ---- Out projection, ring GEMM 256x256 -> bf16 row-major. XCD-swizzled. ----
__global__ __launch_bounds__(512, 2) void k_gemm_out8(
    const unsigned short* __restrict__ A,    // [32768,768] bf16 (ctx)
    const unsigned short* __restrict__ Bw,   // [768,768] bf16
    const float* __restrict__ bias,          // [768]
    unsigned short* __restrict__ outb)       // [32768,768] bf16
{
  extern __shared__ __align__(16) unsigned short lds[];   // 128 KiB
  const int bb = blockIdx.x;                 // 384 blocks
  const int xcd = bb & 7, idx = bb >> 3;     // idx in [0,48)
  const int m0 = (xcd*16 + idx/3) * 256;
  const int n0 = (idx%3) * 256;
  GEMM_RING_KLOOP(A, Bw)

#pragma unroll
  for (int half = 0; half < 2; half++) {
    __syncthreads();
    if (wm == half) {
#pragma unroll
      for (int nf = 0; nf < 4; nf++) {
        const int col = wn*64 + nf*16 + ln;
        const float bi = bias[n0 + col];
        const int cc = col >> 3, cs = col & 7;
#pragma unroll
        for (int mf = 0; mf < 8; mf++) {
          const int row = mf*16 + quad*4;
#pragma unroll
          for (int r = 0; r < 4; r++) {
            const int rw = row + r;
            lds[rw*256 + ((cc ^ (rw&7))<<3) + cs] = f2b(acc[mf][nf][r] + bi);
          }
        }
      }
    }
    __syncthreads();
#pragma unroll
    for (int it = 0; it < 8; it++) {
      int ci = it*512 + tid;
      int r2 = ci >> 5, cj = ci & 31;
      *(uint4*)&outb[(size_t)(m0 + half*128 + r2)*768 + n0 + cj*8] =
          *(const uint4*)&lds[r2*256 + ((cj ^ (r2&7))<<3)];
    }
  }
}

// ---- MFMA attention v2: double-buffered K/V staging (T14/T3 applied).
// 512-thread blocks, 2 blocks per (t,h). 8 waves x 32 q-rows.
// Stage tile it+1 into buf p^1 BEFORE computing tile it; counted vmcnt(2)
// (retires all but the newest 2 loads = exactly the next tile's stage,
// robust to issue reordering); pinned barriers. Staging latency hides
// under the previous tile's QK^T+softmax+PV. LDS dynamic 70 KiB
// (2x16KB KV ring + 36KB Ps + 2KB Dn) -> still 2 blocks/CU.
// Compute path, P layout, accumulation order unchanged -> bitwise-identical.
__global__ __launch_bounds__(512) void k_attn(
    const unsigned short* __restrict__ q,    // [T,H,B,HD]
    const unsigned short* __restrict__ k,    // [T,H,B,HD]
    const unsigned short* __restrict__ vT,   // [T,H,HD,B]
    unsigned short* __restrict__ ctx)        // [T,B,D]
{
  extern __shared__ __align__(16) unsigned short lds[];
  // layout (shorts): [0,8192) buf0 {Ks 4096, VT 4096}; [8192,16384) buf1;
  // [16384,34816) Ps (8 waves x 32 x 72); then Dn (512 floats)
  unsigned short* Ps = lds + 16384;
  float* Dn = (float*)(lds + 34816);
  const int tid = threadIdx.x;
  const int lane = tid & 63, wave = tid >> 6;          // wave 0..7
  const int ln = lane & 15, quad = lane >> 4;
  const int pxr = 8 * (ln >> 2);                       // P column XOR swizzle
  const int bb = blockIdx.x;                 // 1536 blocks
  const int xcd = bb & 7, idx = bb >> 3;     // idx in [0,192)
  const int th = xcd*96 + (idx >> 1);        // t*12+h ; th's 2 blocks share XCD
  const int q0 = (idx & 1) * 256;
  const int t = th / H_, h = th - t*H_;
  const size_t base  = (size_t)th * (B_*HD_);   // q,k base
  const size_t baseT = (size_t)th * (HD_*B_);   // vT base

  // staging thread constants (same conflict-free chunk map as before)
  const int rS = tid >> 3, cS = (tid & 7) ^ (rS & 7);

  // Q fragments: this wave's 32 q-rows (2 subtiles of 16), in registers.
  short8 qf[2][2];
#pragma unroll
  for (int s = 0; s < 2; s++) {
    const unsigned short* qp = &q[base + (size_t)(q0 + wave*32 + s*16 + ln)*HD_ + quad*8];
    qf[s][0] = *(const short8*)qp;
    qf[s][1] = *(const short8*)(qp + 32);
  }
  f32x4 acc[2][4] = {};          // [q-subtile][dim-subtile]
  float dpart[2] = {0.f, 0.f};   // per-lane partial denominators
  unsigned short* Pw = &Ps[wave*32*72];

  // prologue: stage tile 0 into buf0
  load_lds16(&k[base + (size_t)(0 + rS)*HD_ + cS*8], &lds[tid*8]);
  load_lds16(&vT[baseT + (size_t)rS*B_ + 0 + cS*8], &lds[4096 + tid*8]);

  for (int it = 0; it < 8; ++it) {
    const int p = it & 1;
    unsigned short* Ks = &lds[p*8192];
    unsigned short* VTb = &lds[p*8192 + 4096];
    // issue next tile's stage into the other buffer (before compute)
    if (it < 7) {
      const int kt1 = (it+1)*64;
      load_lds16(&k[base + (size_t)(kt1 + rS)*HD_ + cS*8], &lds[(p^1)*8192 + tid*8]);
      load_lds16(&vT[baseT + (size_t)rS*B_ + kt1 + cS*8], &lds[(p^1)*8192 + 4096 + tid*8]);
      WVM2();             // current tile's loads retired; next tile's 2 in flight
    } else {
      WVM0();             // last tile: drain
    }
    BARF();               // publish buf p to all waves
    // QK^T swapped: sf[s][ki] = S^T rows=key(ki*16+quad*4+r), col=qrow(s*16+ln)
    f32x4 sf[2][4] = {};
#pragma unroll
    for (int ki = 0; ki < 4; ki++) {
      int row = ki*16 + ln;
      short8 kf0 = *(const short8*)&Ks[row*64 + (quad     ^ (row & 7))*8];
      short8 kf1 = *(const short8*)&Ks[row*64 + ((4+quad) ^ (row & 7))*8];
#pragma unroll
      for (int s = 0; s < 2; s++) {
        sf[s][ki] = __builtin_amdgcn_mfma_f32_16x16x32_bf16(kf0, qf[s][0], sf[s][ki], 0, 0, 0);
        sf[s][ki] = __builtin_amdgcn_mfma_f32_16x16x32_bf16(kf1, qf[s][1], sf[s][ki], 0, 0, 0);
      }
    }
    // exp (fp32), lane-local denominator, truncate-pack 4 keys -> ds_write_b64
#pragma unroll
    for (int s = 0; s < 2; s++)
#pragma unroll
      for (int ki = 0; ki < 4; ki++) {
        float p0 = __expf(sf[s][ki][0] * 0.125f);
        float p1 = __expf(sf[s][ki][1] * 0.125f);
        float p2 = __expf(sf[s][ki][2] * 0.125f);
        float p3 = __expf(sf[s][ki][3] * 0.125f);
        dpart[s] += (p0 + p1) + (p2 + p3);
        uint2 uu;
        uu.x = (__float_as_uint(p1) & 0xFFFF0000u) | (__float_as_uint(p0) >> 16);
        uu.y = (__float_as_uint(p3) & 0xFFFF0000u) | (__float_as_uint(p2) >> 16);
        int col = (ki*16 + quad*4) ^ pxr;
        *(uint2*)&Pw[(s*16 + ln)*72 + col] = uu;
      }
    // PV: A-frags from Pw[qrow][keys], B-frags from VT packed chunks
    short8 pa[2][2];
#pragma unroll
    for (int s = 0; s < 2; s++)
#pragma unroll
      for (int hf = 0; hf < 2; hf++)
        pa[s][hf] = *(const short8*)&Pw[(s*16 + ln)*72 + ((hf*32 + quad*8) ^ pxr)];
#pragma unroll
    for (int ds = 0; ds < 4; ds++) {
      int row = ds*16 + ln;                  // dim
      short8 vb0 = *(const short8*)&VTb[row*64 + (quad     ^ (row & 7))*8];
      short8 vb1 = *(const short8*)&VTb[row*64 + ((4+quad) ^ (row & 7))*8];
#pragma unroll
      for (int s = 0; s < 2; s++) {
        acc[s][ds] = __builtin_amdgcn_mfma_f32_16x16x32_bf16(pa[s][0], vb0, acc[s][ds], 0, 0, 0);
        acc[s][ds] = __builtin_amdgcn_mfma_f32_16x16x32_bf16(pa[s][1], vb1, acc[s][ds], 0, 0, 0);
      }
    }
    BARF();               // all waves done reading buf p; next iter may restage it
  }
  // denominators: reduce over quad groups (2 shuffles), stash in LDS
#pragma unroll
  for (int s = 0; s < 2; s++) {
    float d = dpart[s];
    d += __shfl_xor(d, 16);
    d += __shfl_xor(d, 32);
    if (quad == 0) Dn[wave*64 + s*16 + ln] = d;
  }
#pragma unroll
  for (int s = 0; s < 2; s++) {
    int qrow = q0 + wave*32 + s*16 + quad*4;
#pragma unroll
    for (int r = 0; r < 4; r++) {
      float invd = 1.f / Dn[wave*64 + s*16 + quad*4 + r];
      size_t o = ((size_t)t*B_ + (qrow + r))*D_ + h*HD_ + ln;
#pragma unroll
      for (int ds = 0; ds < 4; ds++)
        ctx[o + ds*16] = f2b(acc[s][ds][r] * invd);
    }
  }
}

// ---- Norms + partial mean-normalized vectors (bf16 input). 512 blocks. ----
__global__ __launch_bounds__(256) void k_norms1(const unsigned short* __restrict__ outb,
                                                float* __restrict__ norms,
                                                float* __restrict__ pmvec)
{
  __shared__ float wsum[4*768];
  int blk = blockIdx.x;            // t*8 + c
  int t = blk >> 3, c = blk & 7;
  int wave = threadIdx.x >> 6, lane = threadIdx.x & 63;
  float macc[12];
#pragma unroll
  for (int j = 0; j < 12; j++) macc[j] = 0.f;
  for (int i = 0; i < 16; i++) {
    int b = c*64 + wave*16 + i;
    const unsigned short* row = &outb[((size_t)t*B_ + b)*D_];
    float x[12]; float ss = 0.f;
#pragma unroll
    for (int j = 0; j < 12; j++) { x[j] = b2f(row[lane + 64*j]); ss += x[j]*x[j]; }
#pragma unroll
    for (int off = 32; off; off >>= 1) ss += __shfl_xor(ss, off);
    float nr = fmaxf(sqrtf(ss), 1e-8f);
    if (lane == 0) norms[(size_t)t*B_ + b] = nr;
    float inv = 1.f / nr;
#pragma unroll
    for (int j = 0; j < 12; j++) macc[j] += x[j]*inv;
  }
#pragma unroll
  for (int j = 0; j < 12; j++) wsum[wave*768 + 64*j + lane] = macc[j];
  __syncthreads();
  for (int d = threadIdx.x; d < 768; d += 256) {
    pmvec[(size_t)blk*768 + d] = wsum[d] + wsum[768 + d] + wsum[1536 + d] + wsum[2304 + d];
  }
}

// ---- reduce 8 partials -> mvec[t] ----
__global__ __launch_bounds__(256) void k_norms2(const float* __restrict__ pmvec,
                                                float* __restrict__ mvec)
{
  int t = blockIdx.x;
  for (int d = threadIdx.x; d < 768; d += 256) {
    float s = 0.f;
#pragma unroll
    for (int c = 0; c < 8; c++) s += pmvec[(size_t)(t*8 + c)*768 + d];
    mvec[t*768 + d] = s * (1.0f/512.0f);
  }
}

// ---- adj[t,b] = mvec[t] . out[t,b] / norms[t,b]. One wave per row. ----
__global__ __launch_bounds__(256) void k_adj(const unsigned short* __restrict__ outb,
                                             const float* __restrict__ norms,
                                             const float* __restrict__ mvec,
                                             float* __restrict__ adj)
{
  int idx = blockIdx.x*4 + (threadIdx.x >> 6);   // 0..32767
  int lane = threadIdx.x & 63;
  int t = idx >> 9;
  const unsigned short* row = &outb[(size_t)idx*768];
  const float* m = &mvec[t*768];
  float dot = 0.f;
#pragma unroll
  for (int j = 0; j < 12; j++) dot += b2f(row[lane + 64*j]) * m[lane + 64*j];
#pragma unroll
  for (int off = 32; off; off >>= 1) dot += __shfl_xor(dot, off);
  if (lane == 0) adj[idx] = dot / norms[idx];
}

extern "C" void kernel_launch(void* const* d_in, const int* in_sizes, int n_in,
                              void* d_out, int out_size, void* d_ws, size_t ws_size,
                              hipStream_t stream)
{
  const float* node = (const float*)d_in[0];  // (64,512,768)
  const float* wqkv = (const float*)d_in[1];  // (2304,768)
  const float* bqkv = (const float*)d_in[2];  // (2304,)
  const float* wout = (const float*)d_in[3];  // (768,768)
  const float* bout = (const float*)d_in[4];  // (768,)
  float* adj = (float*)d_out;                 // (64,512,1)

  char* ws = (char*)d_ws;
  const size_t SZ = (size_t)M1*D_*2;          // 50,331,648 B
  unsigned short* q_bf    = (unsigned short*)(ws);
  unsigned short* k_bf    = (unsigned short*)(ws + SZ);
  unsigned short* vT_bf   = (unsigned short*)(ws + 2*SZ);
  unsigned short* ctx_bf  = (unsigned short*)(ws + 3*SZ);
  unsigned short* x_bf    = (unsigned short*)(ws + 4*SZ);
  unsigned short* wqkv_bf = (unsigned short*)(ws + 5*SZ);
  unsigned short* wout_bf = (unsigned short*)(ws + 5*SZ + 3538944);
  unsigned short* out_bf  = (unsigned short*)(ws);                          // alias q
  float* pmvec            = (float*)(ws + 4*SZ);                            // alias x_bf
  float* norms            = (float*)(ws + 5*SZ + 3538944 + 1179648);
  float* mvec             = (float*)(ws + 5*SZ + 3538944 + 1179648 + 131072);

  // one-time: allow dynamic LDS (GEMMs 128 KiB; attn 70 KiB)
  static int shmem_set = 0;
  if (!shmem_set) {
    hipFuncSetAttribute((const void*)k_gemm_qkv8,
                        hipFuncAttributeMaxDynamicSharedMemorySize, 131072);
    hipFuncSetAttribute((const void*)k_gemm_out8,
                        hipFuncAttributeMaxDynamicSharedMemorySize, 131072);
    hipFuncSetAttribute((const void*)k_attn,
                        hipFuncAttributeMaxDynamicSharedMemorySize, 71680);
    shmem_set = 1;
  }

  // 1) fused casts to bf16
  k_cast_all<<<26880, 256, 0, stream>>>(node, wqkv, wout, x_bf, wqkv_bf, wout_bf);
  // 2) QKV projection (two-barrier-phase ring, 256^2 tile, 128x64 wave tiles)
  k_gemm_qkv8<<<1152, 512, 131072, stream>>>(x_bf, wqkv_bf, bqkv, q_bf, k_bf, vT_bf);
  // 3) attention (double-buffered K/V staging, counted vmcnt)
  k_attn<<<1536, 512, 71680, stream>>>(q_bf, k_bf, vT_bf, ctx_bf);
  // 4) out projection (ring GEMM) -> bf16 out (aliases q space)
  k_gemm_out8<<<384, 512, 131072, stream>>>(ctx_bf, wout_bf, bout, out_bf);
  // 5) norms + mean normalized vector per t
  k_norms1<<<T_*8, 256, 0, stream>>>(out_bf, norms, pmvec);
  k_norms2<<<T_, 256, 0, stream>>>(pmvec, mvec);
  // 6) adj = mvec . xn
  k_adj<<<M1/4, 256, 0, stream>>>(out_bf, norms, mvec, adj);
}

// Round 16
// 435.521 us; speedup vs baseline: 1.0291x; 1.0291x over previous
//
#include <hip/hip_runtime.h>

// Problem constants
#define T_ 64
#define B_ 512
#define D_ 768
#define H_ 12
#define HD_ 64
#define M1 (T_*B_)        // 32768 rows for both GEMMs
#define N_QKV (3*D_)      // 2304

typedef __attribute__((ext_vector_type(8))) short short8;
typedef __attribute__((ext_vector_type(4))) float f32x4;

__device__ __forceinline__ unsigned short f2b(float f) {
  unsigned int u = __float_as_uint(f);
  u = (u + 0x7FFFu + ((u >> 16) & 1u)) >> 16;   // RNE
  return (unsigned short)u;
}
__device__ __forceinline__ float b2f(unsigned short s) {
  return __uint_as_float(((unsigned int)s) << 16);
}

// async 16B global -> LDS. ALWAYS offset=0 (verified semantics); offsets are
// folded into the global pointer.
__device__ __forceinline__ void load_lds16(const unsigned short* g, unsigned short* l) {
  __builtin_amdgcn_global_load_lds(
      (const __attribute__((address_space(1))) unsigned int*)g,
      (__attribute__((address_space(3))) unsigned int*)l, 16, 0, 0);
}

// ---- fused fp32 -> bf16 casts (node / wqkv / wout in one launch) ----
#define N4_NODE 6291456
#define N4_WQKV 442368
#define N4_WOUT 147456
__global__ __launch_bounds__(256) void k_cast_all(
    const float* __restrict__ node, const float* __restrict__ wqkv,
    const float* __restrict__ wout, unsigned short* __restrict__ x_bf,
    unsigned short* __restrict__ wqkv_bf, unsigned short* __restrict__ wout_bf) {
  int i = blockIdx.x * 256 + threadIdx.x;
  const float* src; unsigned short* dst; int off;
  if (i < N4_NODE)                 { src = node; dst = x_bf;    off = i; }
  else if (i < N4_NODE + N4_WQKV)  { src = wqkv; dst = wqkv_bf; off = i - N4_NODE; }
  else                             { src = wout; dst = wout_bf; off = i - N4_NODE - N4_WQKV; }
  float4 v = ((const float4*)src)[off];
  ushort4 o;
  o.x = f2b(v.x); o.y = f2b(v.y); o.z = f2b(v.z); o.w = f2b(v.w);
  ((ushort4*)dst)[off] = o;
}

#define SB0() __builtin_amdgcn_sched_barrier(0)
#define BARF() do { SB0(); __builtin_amdgcn_s_barrier(); SB0(); } while (0)
#define WLG0() asm volatile("s_waitcnt lgkmcnt(0)" ::: "memory")
#define WVM8() asm volatile("s_waitcnt vmcnt(8)" ::: "memory")
#define WVM6() asm volatile("s_waitcnt vmcnt(6)" ::: "memory")
#define WVM4() asm volatile("s_waitcnt vmcnt(4)" ::: "memory")
#define WVM3() asm volatile("s_waitcnt vmcnt(3)" ::: "memory")
#define WVM2() asm volatile("s_waitcnt vmcnt(2)" ::: "memory")
#define WVM0() asm volatile("s_waitcnt vmcnt(0)" ::: "memory")

// =====================================================================
// QKV GEMM: m201-style two-barrier-phase ring, tile 256x256, K-granule 32
// (24 granules), ring-of-4 x 32 KiB = 128 KiB LDS, stage-ahead 3.
// (Round-11 verified; ~800 TF plateau for this K=768 shape.)
// =====================================================================
// 98304 = 128*768 shorts = 128 source rows.
#define STG_A(SLOT, GOFF) do { \
  load_lds16(Ag + (GOFF),          lds + (SLOT)*16384 + tid*8); \
  load_lds16(Ag + 98304 + (GOFF),  lds + (SLOT)*16384 + 4096 + tid*8); \
} while (0)
#define STG_B(SLOT, GOFF) do { \
  load_lds16(Bg0 + (GOFF),          lds + (SLOT)*16384 + 8192 + tid*8); \
  load_lds16(Bg0 + 98304 + (GOFF),  lds + (SLOT)*16384 + 12288 + tid*8); \
} while (0)

#define RD_ALO(PAR, SLOT) do { \
  const unsigned short* p_ = lds + (SLOT)*16384 + aBase; \
  aLo[PAR][0] = *(const short8*)(p_); \
  aLo[PAR][1] = *(const short8*)(p_ + 512); \
  aLo[PAR][2] = *(const short8*)(p_ + 1024); \
  aLo[PAR][3] = *(const short8*)(p_ + 1536); \
} while (0)

#define RD_BHI(SLOT) do { \
  const unsigned short* pb_ = lds + (SLOT)*16384 + bBase; \
  bC[0] = *(const short8*)(pb_); \
  bC[1] = *(const short8*)(pb_ + 512); \
  bC[2] = *(const short8*)(pb_ + 1024); \
  bC[3] = *(const short8*)(pb_ + 1536); \
  const unsigned short* pa_ = lds + (SLOT)*16384 + aBase + 2048; \
  aHi[0] = *(const short8*)(pa_); \
  aHi[1] = *(const short8*)(pa_ + 512); \
  aHi[2] = *(const short8*)(pa_ + 1024); \
  aHi[3] = *(const short8*)(pa_ + 1536); \
} while (0)

#define MM_LO(PAR) do { \
  __builtin_amdgcn_s_setprio(1); \
  _Pragma("unroll") \
  for (int mf = 0; mf < 4; mf++) \
    _Pragma("unroll") \
    for (int nf = 0; nf < 4; nf++) \
      acc[mf][nf] = __builtin_amdgcn_mfma_f32_16x16x32_bf16(aLo[PAR][mf], bC[nf], acc[mf][nf], 0, 0, 0); \
  __builtin_amdgcn_s_setprio(0); \
} while (0)

#define MM_HI() do { \
  __builtin_amdgcn_s_setprio(1); \
  _Pragma("unroll") \
  for (int mf = 0; mf < 4; mf++) \
    _Pragma("unroll") \
    for (int nf = 0; nf < 4; nf++) \
      acc[4+mf][nf] = __builtin_amdgcn_mfma_f32_16x16x32_bf16(aHi[mf], bC[nf], acc[4+mf][nf], 0, 0, 0); \
  __builtin_amdgcn_s_setprio(0); \
} while (0)

#define P0(SLOT, PAR, SSLOT, GOFF, WVSTMT) do { \
  RD_BHI(SLOT); STG_A(SSLOT, GOFF); WVSTMT; BARF(); WLG0(); MM_LO(PAR); BARF(); \
} while (0)
#define P1(NPAR, NSLOT, SSLOT, GOFF) do { \
  RD_ALO(NPAR, NSLOT); STG_B(SSLOT, GOFF); BARF(); MM_HI(); BARF(); \
} while (0)

#define GEMM_RING_KLOOP(Aptr, Bptr) \
  const int tid = threadIdx.x; \
  const int lane = tid & 63, wave = tid >> 6; \
  const int ln = lane & 15, quad = lane >> 4; \
  const int wm = wave & 1, wn = wave >> 1; \
  const int w_ = tid & 7, g_ = tid >> 3; \
  const int rowS_ = ((g_ >> 2) << 3) + (w_ & 4) + (g_ & 3); \
  const int octS_ = (w_ & 3) ^ (g_ & 3); \
  const unsigned short* Ag = Aptr + (size_t)(m0 + rowS_)*768 + octS_*8; \
  const unsigned short* Bg0 = Bptr + (size_t)(n0 + rowS_)*768 + octS_*8; \
  const int inner_ = (((ln>>3)*4 + (ln&3))*8 + ((ln&7) ^ quad)) * 8; \
  const int aBase = wm*4096 + inner_; \
  const int bBase = 8192 + (wn>>1)*4096 + (wn&1)*2048 + inner_; \
  short8 aLo[2][4], aHi[4], bC[4]; \
  f32x4 acc[8][4] = {}; \
  STG_A(0, 0); STG_B(0, 0); STG_A(1, 32); STG_B(1, 32); STG_A(2, 64); STG_B(2, 64); \
  WVM8(); BARF(); \
  RD_ALO(0, 0); \
  P0(0, 0, 3, 96, WVM6()); \
  P1(1, 1, 3, 96); \
  for (int J = 0; J < 5; ++J) { \
    P0(1, 1, 0, 128, WVM6()); \
    P1(0, 2, 0, 128); \
    P0(2, 0, 1, 160, WVM6()); \
    P1(1, 3, 1, 160); \
    P0(3, 1, 2, 192, WVM6()); \
    P1(0, 0, 2, 192); \
    P0(0, 0, 3, 224, WVM6()); \
    P1(1, 1, 3, 224); \
    Ag += 128; Bg0 += 128; \
  } \
  RD_BHI(1); WVM4(); BARF(); WLG0(); MM_LO(1); BARF(); \
  RD_ALO(0, 2); BARF(); MM_HI(); BARF(); \
  RD_BHI(2); WVM0(); BARF(); WLG0(); MM_LO(0); BARF(); \
  RD_ALO(1, 3); BARF(); MM_HI(); BARF(); \
  RD_BHI(3); BARF(); WLG0(); MM_LO(1); BARF(); \
  MM_HI(); \
  __syncthreads();

// ---- QKV projection, ring GEMM 256x256. XCD-swizzled; LDS-repack epilogues.
__global__ __launch_bounds__(512, 2) void k_gemm_qkv8(
    const unsigned short* __restrict__ A,    // [32768,768] bf16
    const unsigned short* __restrict__ Bw,   // [2304,768]  bf16
    const float* __restrict__ bias,          // [2304]
    unsigned short* __restrict__ qo,
    unsigned short* __restrict__ ko,
    unsigned short* __restrict__ vTo)
{
  extern __shared__ __align__(16) unsigned short lds[];   // 128 KiB
  const int bb = blockIdx.x;                 // 1152 blocks
  const int xcd = bb & 7, idx = bb >> 3;     // idx in [0,144)
  const int m0 = (xcd*16 + idx/9) * 256;     // same-XCD blocks share m-stripe
  const int n0 = (idx%9) * 256;              // n sweeps fastest -> A L2 reuse
  GEMM_RING_KLOOP(A, Bw)

  const int t = m0 >> 9, mb = m0 & 511;
  if (n0 < 1536) {
    // q/k: two 128-row halves; repack [row][col] (chunk^row swizzle) + store
    unsigned short* dst = (n0 < 768) ? qo : ko;
    const int colbase = (n0 < 768) ? n0 : n0 - 768;
#pragma unroll
    for (int half = 0; half < 2; half++) {
      __syncthreads();
      if (wm == half) {
#pragma unroll
        for (int nf = 0; nf < 4; nf++) {
          const int col = wn*64 + nf*16 + ln;
          const float bi = bias[n0 + col];
          const int cc = col >> 3, cs = col & 7;
#pragma unroll
          for (int mf = 0; mf < 8; mf++) {
            const int row = mf*16 + quad*4;       // local to half
#pragma unroll
            for (int r = 0; r < 4; r++) {
              const int rw = row + r;
              lds[rw*256 + ((cc ^ (rw&7))<<3) + cs] = f2b(acc[mf][nf][r] + bi);
            }
          }
        }
      }
      __syncthreads();
#pragma unroll
      for (int it = 0; it < 8; it++) {
        int ci = it*512 + tid;
        int r2 = ci >> 5, cj = ci & 31;
        int within = colbase + cj*8;
        int h = within >> 6, hd = within & 63;
        *(uint4*)&dst[((size_t)(t*H_ + h)*B_ + mb + half*128 + r2)*HD_ + hd] =
            *(const uint4*)&lds[r2*256 + ((cj ^ (r2&7))<<3)];
      }
    }
  } else {
    // v: two 128-col halves; repack transposed [col][b-row] + store
#pragma unroll
    for (int ch = 0; ch < 2; ch++) {
      __syncthreads();
      if ((wn >> 1) == ch) {
#pragma unroll
        for (int nf = 0; nf < 4; nf++) {
          const int col = wn*64 + nf*16 + ln;
          const int cl = col & 127;               // local to col-half
          const float bi = bias[n0 + col];
#pragma unroll
          for (int mf = 0; mf < 8; mf++) {
            const int row = wm*128 + mf*16 + quad*4;   // 0..255
            ushort4 pk;
            pk.x = f2b(acc[mf][nf][0] + bi);
            pk.y = f2b(acc[mf][nf][1] + bi);
            pk.z = f2b(acc[mf][nf][2] + bi);
            pk.w = f2b(acc[mf][nf][3] + bi);
            *(ushort4*)&lds[cl*256 + (((row>>3) ^ (cl&7))<<3) + (row&7)] = pk;
          }
        }
      }
      __syncthreads();
#pragma unroll
      for (int it = 0; it < 8; it++) {
        int ci = it*512 + tid;
        int r2 = ci >> 5, cj = ci & 31;     // r2 = col-local, cj = b-chunk
        int cg = (n0 - 1536) + ch*128 + r2;
        int h = cg >> 6, hd = cg & 63;
        *(uint4*)&vTo[((size_t)(t*H_ + h)*HD_ + hd)*B_ + mb + cj*8] =
            *(const uint4*)&lds[r2*256 + ((cj ^ (r2&7))<<3)];
      }
    }
  }
}

// =====================================================================
// Out-proj GEMM: round-6/7 verified 128x256 ring-of-4 (granule 12288
// shorts, vmcnt 6/3/0, conflict-free slot map). 768 blocks = 3 FULL
// rounds on 256 CUs (fixes the 384-block 1.5-round imbalance).
// Accumulation order: one MFMA per granule per element, increasing g —
// identical to all prior passing kernels -> bitwise-identical output.
// =====================================================================
#define STG7(SLOT, GOFF) do { \
  load_lds16(Ag + (GOFF),  lds + (SLOT)*12288 + tid*8); \
  load_lds16(Bg0 + (GOFF), lds + (SLOT)*12288 + 4096 + tid*8); \
  load_lds16(Bg1 + (GOFF), lds + (SLOT)*12288 + 8192 + tid*8); \
} while (0)

#define RD7(GU) do { \
  const unsigned short* ga_ = lds + (GU)*12288; \
  aF[0] = *(const short8*)(ga_ + aBase); \
  aF[1] = *(const short8*)(ga_ + aBase + 512); \
  aF[2] = *(const short8*)(ga_ + aBase + 1024); \
  aF[3] = *(const short8*)(ga_ + aBase + 1536); \
  bF[0] = *(const short8*)(ga_ + bBase); \
  bF[1] = *(const short8*)(ga_ + bBase + 512); \
  bF[2] = *(const short8*)(ga_ + bBase + 1024); \
  bF[3] = *(const short8*)(ga_ + bBase + 1536); \
} while (0)

#define MM7() do { \
  __builtin_amdgcn_s_setprio(1); \
  _Pragma("unroll") \
  for (int mf = 0; mf < 4; mf++) \
    _Pragma("unroll") \
    for (int nf = 0; nf < 4; nf++) \
      acc[mf][nf] = __builtin_amdgcn_mfma_f32_16x16x32_bf16(aF[mf], bF[nf], acc[mf][nf], 0, 0, 0); \
  __builtin_amdgcn_s_setprio(0); \
} while (0)

#define PH7(GU, GOFF) do { RD7(GU); STG7(((GU)+3)&3, GOFF); WVM6(); WLG0(); MM7(); BARF(); } while (0)

__global__ __launch_bounds__(512, 2) void k_gemm_out8(
    const unsigned short* __restrict__ A,    // [32768,768] bf16 (ctx)
    const unsigned short* __restrict__ Bw,   // [768,768] bf16
    const float* __restrict__ bias,          // [768]
    unsigned short* __restrict__ outb)       // [32768,768] bf16
{
  extern __shared__ __align__(16) unsigned short lds[];   // 96 KiB
  const int bb = blockIdx.x;                 // 768 blocks
  const int xcd = bb & 7, idx = bb >> 3;     // idx in [0,96)
  const int m0 = (xcd*32 + idx/3) * 128;
  const int n0 = (idx%3) * 256;

  const int tid = threadIdx.x;
  const int lane = tid & 63, wave = tid >> 6;
  const int ln = lane & 15, quad = lane >> 4;
  const int wm = wave & 1, wn = wave >> 1;
  const int w_ = tid & 7, g_ = tid >> 3;
  const int rowS_ = ((g_ >> 2) << 3) + (w_ & 4) + (g_ & 3);
  const int octS_ = (w_ & 3) ^ (g_ & 3);
  const unsigned short* Ag = A + (size_t)(m0 + rowS_)*768 + octS_*8;
  const unsigned short* Bg0 = Bw + (size_t)(n0 + rowS_)*768 + octS_*8;
  const unsigned short* Bg1 = Bg0 + (size_t)128*768;
  const int ra_ = wm*64 + ln;
  const int aBase = ((((ra_>>3)*4 + (ra_&3))*8) + ((ra_&7) ^ quad)) * 8;
  const int rb_ = (wn & 1)*64 + ln;
  const int bBase = 4096 + (wn>>1)*4096 + ((((rb_>>3)*4 + (rb_&3))*8) + ((rb_&7) ^ quad)) * 8;
  short8 aF[4], bF[4];
  f32x4 acc[4][4] = {};
  STG7(0, 0); STG7(1, 32); STG7(2, 64);
  WVM6(); BARF();
  for (int J = 0; J < 5; ++J) {
    PH7(0, 96); PH7(1, 128); PH7(2, 160); PH7(3, 192);
    Ag += 128; Bg0 += 128; Bg1 += 128;
  }
  RD7(0); STG7(3, 96); WVM6(); WLG0(); MM7(); BARF();
  RD7(1); WVM3(); WLG0(); MM7(); BARF();
  RD7(2); WVM0(); WLG0(); MM7(); BARF();
  RD7(3); WLG0(); MM7();
  __syncthreads();

#pragma unroll
  for (int nf = 0; nf < 4; nf++) {
    const int col = wn*64 + nf*16 + ln;
    const float bi = bias[n0 + col];
    const int cc = col >> 3, cs = col & 7;
#pragma unroll
    for (int mf = 0; mf < 4; mf++) {
      const int row = wm*64 + mf*16 + quad*4;
#pragma unroll
      for (int r = 0; r < 4; r++) {
        const int rw = row + r;
        lds[rw*256 + ((cc ^ (rw&7))<<3) + cs] = f2b(acc[mf][nf][r] + bi);
      }
    }
  }
  __syncthreads();
#pragma unroll
  for (int it = 0; it < 8; it++) {
    int ci = it*512 + tid;
    int r2 = ci >> 5, cj = ci & 31;
    *(uint4*)&outb[(size_t)(m0 + r2)*768 + n0 + cj*8] =
        *(const uint4*)&lds[r2*256 + ((cj ^ (r2&7))<<3)];
  }
}

// ---- MFMA attention v2: double-buffered K/V staging (kept from round 12;
// ~33 us gain by subtraction). Counted vmcnt(2), pinned barriers.
__global__ __launch_bounds__(512) void k_attn(
    const unsigned short* __restrict__ q,    // [T,H,B,HD]
    const unsigned short* __restrict__ k,    // [T,H,B,HD]
    const unsigned short* __restrict__ vT,   // [T,H,HD,B]
    unsigned short* __restrict__ ctx)        // [T,B,D]
{
  extern __shared__ __align__(16) unsigned short lds[];
  unsigned short* Ps = lds + 16384;
  float* Dn = (float*)(lds + 34816);
  const int tid = threadIdx.x;
  const int lane = tid & 63, wave = tid >> 6;          // wave 0..7
  const int ln = lane & 15, quad = lane >> 4;
  const int pxr = 8 * (ln >> 2);                       // P column XOR swizzle
  const int bb = blockIdx.x;                 // 1536 blocks
  const int xcd = bb & 7, idx = bb >> 3;     // idx in [0,192)
  const int th = xcd*96 + (idx >> 1);        // t*12+h ; th's 2 blocks share XCD
  const int q0 = (idx & 1) * 256;
  const int t = th / H_, h = th - t*H_;
  const size_t base  = (size_t)th * (B_*HD_);   // q,k base
  const size_t baseT = (size_t)th * (HD_*B_);   // vT base

  const int rS = tid >> 3, cS = (tid & 7) ^ (rS & 7);

  short8 qf[2][2];
#pragma unroll
  for (int s = 0; s < 2; s++) {
    const unsigned short* qp = &q[base + (size_t)(q0 + wave*32 + s*16 + ln)*HD_ + quad*8];
    qf[s][0] = *(const short8*)qp;
    qf[s][1] = *(const short8*)(qp + 32);
  }
  f32x4 acc[2][4] = {};
  float dpart[2] = {0.f, 0.f};
  unsigned short* Pw = &Ps[wave*32*72];

  load_lds16(&k[base + (size_t)(0 + rS)*HD_ + cS*8], &lds[tid*8]);
  load_lds16(&vT[baseT + (size_t)rS*B_ + 0 + cS*8], &lds[4096 + tid*8]);

  for (int it = 0; it < 8; ++it) {
    const int p = it & 1;
    unsigned short* Ks = &lds[p*8192];
    unsigned short* VTb = &lds[p*8192 + 4096];
    if (it < 7) {
      const int kt1 = (it+1)*64;
      load_lds16(&k[base + (size_t)(kt1 + rS)*HD_ + cS*8], &lds[(p^1)*8192 + tid*8]);
      load_lds16(&vT[baseT + (size_t)rS*B_ + kt1 + cS*8], &lds[(p^1)*8192 + 4096 + tid*8]);
      WVM2();
    } else {
      WVM0();
    }
    BARF();
    f32x4 sf[2][4] = {};
#pragma unroll
    for (int ki = 0; ki < 4; ki++) {
      int row = ki*16 + ln;
      short8 kf0 = *(const short8*)&Ks[row*64 + (quad     ^ (row & 7))*8];
      short8 kf1 = *(const short8*)&Ks[row*64 + ((4+quad) ^ (row & 7))*8];
#pragma unroll
      for (int s = 0; s < 2; s++) {
        sf[s][ki] = __builtin_amdgcn_mfma_f32_16x16x32_bf16(kf0, qf[s][0], sf[s][ki], 0, 0, 0);
        sf[s][ki] = __builtin_amdgcn_mfma_f32_16x16x32_bf16(kf1, qf[s][1], sf[s][ki], 0, 0, 0);
      }
    }
#pragma unroll
    for (int s = 0; s < 2; s++)
#pragma unroll
      for (int ki = 0; ki < 4; ki++) {
        float p0 = __expf(sf[s][ki][0] * 0.125f);
        float p1 = __expf(sf[s][ki][1] * 0.125f);
        float p2 = __expf(sf[s][ki][2] * 0.125f);
        float p3 = __expf(sf[s][ki][3] * 0.125f);
        dpart[s] += (p0 + p1) + (p2 + p3);
        uint2 uu;
        uu.x = (__float_as_uint(p1) & 0xFFFF0000u) | (__float_as_uint(p0) >> 16);
        uu.y = (__float_as_uint(p3) & 0xFFFF0000u) | (__float_as_uint(p2) >> 16);
        int col = (ki*16 + quad*4) ^ pxr;
        *(uint2*)&Pw[(s*16 + ln)*72 + col] = uu;
      }
    short8 pa[2][2];
#pragma unroll
    for (int s = 0; s < 2; s++)
#pragma unroll
      for (int hf = 0; hf < 2; hf++)
        pa[s][hf] = *(const short8*)&Pw[(s*16 + ln)*72 + ((hf*32 + quad*8) ^ pxr)];
#pragma unroll
    for (int ds = 0; ds < 4; ds++) {
      int row = ds*16 + ln;
      short8 vb0 = *(const short8*)&VTb[row*64 + (quad     ^ (row & 7))*8];
      short8 vb1 = *(const short8*)&VTb[row*64 + ((4+quad) ^ (row & 7))*8];
#pragma unroll
      for (int s = 0; s < 2; s++) {
        acc[s][ds] = __builtin_amdgcn_mfma_f32_16x16x32_bf16(pa[s][0], vb0, acc[s][ds], 0, 0, 0);
        acc[s][ds] = __builtin_amdgcn_mfma_f32_16x16x32_bf16(pa[s][1], vb1, acc[s][ds], 0, 0, 0);
      }
    }
    BARF();
  }
#pragma unroll
  for (int s = 0; s < 2; s++) {
    float d = dpart[s];
    d += __shfl_xor(d, 16);
    d += __shfl_xor(d, 32);
    if (quad == 0) Dn[wave*64 + s*16 + ln] = d;
  }
#pragma unroll
  for (int s = 0; s < 2; s++) {
    int qrow = q0 + wave*32 + s*16 + quad*4;
#pragma unroll
    for (int r = 0; r < 4; r++) {
      float invd = 1.f / Dn[wave*64 + s*16 + quad*4 + r];
      size_t o = ((size_t)t*B_ + (qrow + r))*D_ + h*HD_ + ln;
#pragma unroll
      for (int ds = 0; ds < 4; ds++)
        ctx[o + ds*16] = f2b(acc[s][ds][r] * invd);
    }
  }
}

// ---- Norms + partial mean-normalized vectors (bf16 input). 512 blocks. ----
__global__ __launch_bounds__(256) void k_norms1(const unsigned short* __restrict__ outb,
                                                float* __restrict__ norms,
                                                float* __restrict__ pmvec)
{
  __shared__ float wsum[4*768];
  int blk = blockIdx.x;            // t*8 + c
  int t = blk >> 3, c = blk & 7;
  int wave = threadIdx.x >> 6, lane = threadIdx.x & 63;
  float macc[12];
#pragma unroll
  for (int j = 0; j < 12; j++) macc[j] = 0.f;
  for (int i = 0; i < 16; i++) {
    int b = c*64 + wave*16 + i;
    const unsigned short* row = &outb[((size_t)t*B_ + b)*D_];
    float x[12]; float ss = 0.f;
#pragma unroll
    for (int j = 0; j < 12; j++) { x[j] = b2f(row[lane + 64*j]); ss += x[j]*x[j]; }
#pragma unroll
    for (int off = 32; off; off >>= 1) ss += __shfl_xor(ss, off);
    float nr = fmaxf(sqrtf(ss), 1e-8f);
    if (lane == 0) norms[(size_t)t*B_ + b] = nr;
    float inv = 1.f / nr;
#pragma unroll
    for (int j = 0; j < 12; j++) macc[j] += x[j]*inv;
  }
#pragma unroll
  for (int j = 0; j < 12; j++) wsum[wave*768 + 64*j + lane] = macc[j];
  __syncthreads();
  for (int d = threadIdx.x; d < 768; d += 256) {
    pmvec[(size_t)blk*768 + d] = wsum[d] + wsum[768 + d] + wsum[1536 + d] + wsum[2304 + d];
  }
}

// ---- reduce 8 partials -> mvec[t] ----
__global__ __launch_bounds__(256) void k_norms2(const float* __restrict__ pmvec,
                                                float* __restrict__ mvec)
{
  int t = blockIdx.x;
  for (int d = threadIdx.x; d < 768; d += 256) {
    float s = 0.f;
#pragma unroll
    for (int c = 0; c < 8; c++) s += pmvec[(size_t)(t*8 + c)*768 + d];
    mvec[t*768 + d] = s * (1.0f/512.0f);
  }
}

// ---- adj[t,b] = mvec[t] . out[t,b] / norms[t,b]. One wave per row. ----
__global__ __launch_bounds__(256) void k_adj(const unsigned short* __restrict__ outb,
                                             const float* __restrict__ norms,
                                             const float* __restrict__ mvec,
                                             float* __restrict__ adj)
{
  int idx = blockIdx.x*4 + (threadIdx.x >> 6);   // 0..32767
  int lane = threadIdx.x & 63;
  int t = idx >> 9;
  const unsigned short* row = &outb[(size_t)idx*768];
  const float* m = &mvec[t*768];
  float dot = 0.f;
#pragma unroll
  for (int j = 0; j < 12; j++) dot += b2f(row[lane + 64*j]) * m[lane + 64*j];
#pragma unroll
  for (int off = 32; off; off >>= 1) dot += __shfl_xor(dot, off);
  if (lane == 0) adj[idx] = dot / norms[idx];
}

extern "C" void kernel_launch(void* const* d_in, const int* in_sizes, int n_in,
                              void* d_out, int out_size, void* d_ws, size_t ws_size,
                              hipStream_t stream)
{
  const float* node = (const float*)d_in[0];  // (64,512,768)
  const float* wqkv = (const float*)d_in[1];  // (2304,768)
  const float* bqkv = (const float*)d_in[2];  // (2304,)
  const float* wout = (const float*)d_in[3];  // (768,768)
  const float* bout = (const float*)d_in[4];  // (768,)
  float* adj = (float*)d_out;                 // (64,512,1)

  char* ws = (char*)d_ws;
  const size_t SZ = (size_t)M1*D_*2;          // 50,331,648 B
  unsigned short* q_bf    = (unsigned short*)(ws);
  unsigned short* k_bf    = (unsigned short*)(ws + SZ);
  unsigned short* vT_bf   = (unsigned short*)(ws + 2*SZ);
  unsigned short* ctx_bf  = (unsigned short*)(ws + 3*SZ);
  unsigned short* x_bf    = (unsigned short*)(ws + 4*SZ);
  unsigned short* wqkv_bf = (unsigned short*)(ws + 5*SZ);
  unsigned short* wout_bf = (unsigned short*)(ws + 5*SZ + 3538944);
  unsigned short* out_bf  = (unsigned short*)(ws);                          // alias q
  float* pmvec            = (float*)(ws + 4*SZ);                            // alias x_bf
  float* norms            = (float*)(ws + 5*SZ + 3538944 + 1179648);
  float* mvec             = (float*)(ws + 5*SZ + 3538944 + 1179648 + 131072);

  // one-time: allow dynamic LDS (qkv 128 KiB; out 96 KiB; attn 70 KiB)
  static int shmem_set = 0;
  if (!shmem_set) {
    hipFuncSetAttribute((const void*)k_gemm_qkv8,
                        hipFuncAttributeMaxDynamicSharedMemorySize, 131072);
    hipFuncSetAttribute((const void*)k_gemm_out8,
                        hipFuncAttributeMaxDynamicSharedMemorySize, 98304);
    hipFuncSetAttribute((const void*)k_attn,
                        hipFuncAttributeMaxDynamicSharedMemorySize, 71680);
    shmem_set = 1;
  }

  // 1) fused casts to bf16
  k_cast_all<<<26880, 256, 0, stream>>>(node, wqkv, wout, x_bf, wqkv_bf, wout_bf);
  // 2) QKV projection (two-barrier-phase ring, 256^2 tile, 128x64 wave tiles)
  k_gemm_qkv8<<<1152, 512, 131072, stream>>>(x_bf, wqkv_bf, bqkv, q_bf, k_bf, vT_bf);
  // 3) attention (double-buffered K/V staging, counted vmcnt)
  k_attn<<<1536, 512, 71680, stream>>>(q_bf, k_bf, vT_bf, ctx_bf);
  // 4) out projection (128x256 ring, 768 blocks = 3 full rounds)
  k_gemm_out8<<<768, 512, 98304, stream>>>(ctx_bf, wout_bf, bout, out_bf);
  // 5) norms + mean normalized vector per t
  k_norms1<<<T_*8, 256, 0, stream>>>(out_bf, norms, pmvec);
  k_norms2<<<T_, 256, 0, stream>>>(pmvec, mvec);
  // 6) adj = mvec . xn
  k_adj<<<M1/4, 256, 0, stream>>>(out_bf, norms, mvec, adj);
}